// Round 1
// baseline (41.829 us; speedup 1.0000x reference)
//
#include <hip/hip_runtime.h>
#include <hip/hip_bf16.h>

// Problem constants
#define PM 8        // groups
#define PK 4096     // codebook entries per group
#define PD 128      // dim
#define PN 8
#define PH 64
#define PW 64

typedef __attribute__((ext_vector_type(8))) short bf16x8;
typedef __attribute__((ext_vector_type(4))) float f32x4;
typedef __attribute__((ext_vector_type(8))) short short8v;

__device__ inline unsigned short f2bf_rne(float f) {
    unsigned int u = __float_as_uint(f);
    unsigned int r = (u + 0x7FFFu + ((u >> 16) & 1u)) >> 16;
    return (unsigned short)r;
}
__device__ inline float bf2f(unsigned short s) {
    return __uint_as_float(((unsigned int)s) << 16);
}

__device__ inline bf16x8 loadcvt8(const float* __restrict__ p) {
    f32x4 x0 = *(const f32x4*)p;
    f32x4 x1 = *(const f32x4*)(p + 4);
    bf16x8 r;
#pragma unroll
    for (int j = 0; j < 4; ++j) {
        r[j]     = (short)f2bf_rne(x0[j]);
        r[j + 4] = (short)f2bf_rne(x1[j]);
    }
    return r;
}

// ---------------------------------------------------------------------------
// Kernel 1: table[m,k,c] = sum_d codebook[m,k,d]*wq[m,c,d] + bq[m,c]  (bf16)
// 8 GEMMs of (4096 x 128) x (128 x 128)^T, K=128, via mfma_f32_16x16x32_bf16.
// Grid: 256 blocks (m = b&7, ktile = (b>>3)*128), 256 threads = 4 waves,
// each wave computes 32 k-rows x 128 c.
// ---------------------------------------------------------------------------
__global__ __launch_bounds__(256) void build_table(
        const float* __restrict__ codebook,
        const float* __restrict__ wq,
        const float* __restrict__ bq,
        unsigned short* __restrict__ table) {
    const int b = blockIdx.x;
    const int m = b & 7;
    const int ktile = (b >> 3) * 128;
    const int tid = threadIdx.x;
    const int wv = tid >> 6;       // wave 0..3
    const int l  = tid & 63;
    const int lr = l & 15;         // frag row/col index
    const int lg = l >> 4;         // k-chunk group 0..3

    const float* cb = codebook + (size_t)m * PK * PD;
    const float* wm = wq + (size_t)m * PD * PD;

    // A fragments: 2 k-subtiles x 4 K-steps, 8 contiguous fp32 along d each.
    bf16x8 afrag[2][4];
#pragma unroll
    for (int ks = 0; ks < 2; ++ks) {
        const int k = ktile + wv * 32 + ks * 16 + lr;
        const float* src = cb + (size_t)k * PD + lg * 8;
#pragma unroll
        for (int kk = 0; kk < 4; ++kk) {
            afrag[ks][kk] = loadcvt8(src + kk * 32);
        }
    }

#pragma unroll
    for (int cs = 0; cs < 8; ++cs) {
        const int c = cs * 16 + lr;
        bf16x8 bfrag[4];
        const float* src = wm + (size_t)c * PD + lg * 8;
#pragma unroll
        for (int kk = 0; kk < 4; ++kk) {
            bfrag[kk] = loadcvt8(src + kk * 32);
        }
        const float bias = bq[m * PD + c];
#pragma unroll
        for (int ks = 0; ks < 2; ++ks) {
            f32x4 acc = {0.f, 0.f, 0.f, 0.f};
#pragma unroll
            for (int kk = 0; kk < 4; ++kk) {
                acc = __builtin_amdgcn_mfma_f32_16x16x32_bf16(
                        afrag[ks][kk], bfrag[kk], acc, 0, 0, 0);
            }
            // C/D layout: col = lane&15, row = (lane>>4)*4 + j   [m89 verified]
            const int kb = ktile + wv * 32 + ks * 16 + lg * 4;
            unsigned short* dst = table + ((size_t)(m * PK + kb)) * PD + cs * 16 + lr;
#pragma unroll
            for (int j = 0; j < 4; ++j) {
                dst[(size_t)j * PD] = f2bf_rne(acc[j] + bias);
            }
        }
    }
}

// ---------------------------------------------------------------------------
// Kernel 2: out[n, m*128+c, h, w] = table[m, codes[n,h,w,m], c]
// Grid: 4096 blocks; m = b&7 (XCD affinity: 1MB table slice per XCD L2),
// then (n,h). 256 threads: lane = w (coalesced stores), 4 waves cover c in
// chunks of 32. Per-lane 16B vector gathers from bf16 table; nontemporal
// output stores (write-once 128MB stream, keep table L2-resident).
// ---------------------------------------------------------------------------
__global__ __launch_bounds__(256) void gather_scatter(
        const int* __restrict__ codes,
        const unsigned short* __restrict__ table,
        float* __restrict__ out) {
    const int b = blockIdx.x;
    const int m = b & 7;
    const int rest = b >> 3;
    const int n = rest >> 6;
    const int h = rest & 63;
    const int tid = threadIdx.x;
    const int w = tid & 63;
    const int cb0 = (tid >> 6) * 32;   // 0,32,64,96 per wave

    const int code = codes[((n * PH + h) * PW + w) * PM + m];
    const unsigned short* row = table + ((size_t)m * PK + code) * PD + cb0;
    float* ob = out + (((size_t)n * (PM * PD) + m * PD + cb0) * PH + h) * PW + w;

#pragma unroll
    for (int i = 0; i < 4; ++i) {
        short8v v = *(const short8v*)(row + i * 8);
#pragma unroll
        for (int j = 0; j < 8; ++j) {
            __builtin_nontemporal_store(bf2f((unsigned short)v[j]),
                                        ob + (size_t)(i * 8 + j) * (PH * PW));
        }
    }
}

// ---------------------------------------------------------------------------
// Fallback (only if ws_size < table size): fused direct compute, fp32.
// ---------------------------------------------------------------------------
__global__ __launch_bounds__(256) void fused_direct(
        const int* __restrict__ codes,
        const float* __restrict__ codebook,
        const float* __restrict__ wq,
        const float* __restrict__ bq,
        float* __restrict__ out) {
    __shared__ float rows[PW][133];   // +5 pad: (w*133+d)%32 = (5w+d)%32, 2-way free
    const int b = blockIdx.x;
    const int m = b & 7;
    const int rest = b >> 3;
    const int n = rest >> 6;
    const int h = rest & 63;
    const int tid = threadIdx.x;

    for (int idx = tid; idx < PW * 32; idx += 256) {
        const int r = idx >> 5;
        const int e = (idx & 31) * 4;
        const int code = codes[((n * PH + h) * PW + r) * PM + m];
        const float* src = codebook + ((size_t)m * PK + code) * PD + e;
#pragma unroll
        for (int j = 0; j < 4; ++j) rows[r][e + j] = src[j];
    }
    __syncthreads();

    const int w = tid & 63;
    const int cb0 = (tid >> 6) * 32;
    float* ob = out + (((size_t)n * (PM * PD) + m * PD + cb0) * PH + h) * PW + w;
    for (int ci = 0; ci < 32; ++ci) {
        const int c = cb0 + ci;
        const float* wr = wq + ((size_t)m * PD + c) * PD;
        float acc = bq[m * PD + c];
#pragma unroll 4
        for (int d = 0; d < PD; ++d) acc += rows[w][d] * wr[d];
        ob[(size_t)ci * (PH * PW)] = acc;
    }
}

extern "C" void kernel_launch(void* const* d_in, const int* in_sizes, int n_in,
                              void* d_out, int out_size, void* d_ws, size_t ws_size,
                              hipStream_t stream) {
    const int*   codes    = (const int*)  d_in[0];
    const float* codebook = (const float*)d_in[1];
    const float* wq       = (const float*)d_in[2];
    const float* bq       = (const float*)d_in[3];
    float* out = (float*)d_out;

    const size_t table_bytes = (size_t)PM * PK * PD * sizeof(unsigned short); // 8 MB
    if (ws_size >= table_bytes) {
        unsigned short* table = (unsigned short*)d_ws;
        build_table<<<dim3(256), dim3(256), 0, stream>>>(codebook, wq, bq, table);
        gather_scatter<<<dim3(PM * PN * PH), dim3(256), 0, stream>>>(codes, table, out);
    } else {
        fused_direct<<<dim3(PM * PN * PH), dim3(256), 0, stream>>>(codes, codebook, wq, bq, out);
    }
}